// Round 7
// baseline (355.648 us; speedup 1.0000x reference)
//
#include <hip/hip_runtime.h>

typedef __attribute__((ext_vector_type(8))) short bf8_t;   // 8 x bf16 (4 VGPRs)
typedef __attribute__((ext_vector_type(4))) short bf4_t;   // 4 x bf16 (2 VGPRs)
typedef __attribute__((ext_vector_type(4))) float f4_t;    // 4 x fp32 acc
typedef unsigned short u16;
typedef unsigned int u32;

#define MFMA16 __builtin_amdgcn_mfma_f32_16x16x32_bf16

#define RSQRT8    0.35355339059327373f
#define RSQRT128  0.08838834764831845f
#define RSQRT192  0.07216878364870323f
#define RSQRT64   0.125f
#define INV_SQRT3 0.57735026918962576f
#define SEG_NORM  0.25f       /* 1/sqrt(16) */
#define C_HALF    0.70710678118654752f
#define SQ23      0.81649658092772603f
#define SQ13      0.57735026918962576f

__device__ __forceinline__ float bf2f(u16 b) {
    return __uint_as_float(((u32)b) << 16);
}
// software RNE (cold paths only; bit-identical to HW cvt)
__device__ __forceinline__ u16 f2bf(float f) {
    u32 u = __float_as_uint(f);
    u += 0x7FFFu + ((u >> 16) & 1u);
    return (u16)(u >> 16);
}
// hardware RNE pack: lo -> bits[15:0], hi -> bits[31:16]; 1 VALU inst
__device__ __forceinline__ u32 cvtpk(float lo, float hi) {
    u32 r;
    asm("v_cvt_pk_bf16_f32 %0, %1, %2" : "=v"(r) : "v"(lo), "v"(hi));
    return r;
}
__device__ __forceinline__ u16 f2bf_hw(float f) { return (u16)cvtpk(f, f); }
__device__ __forceinline__ float silu_f(float x) {
    return x * __builtin_amdgcn_rcpf(1.0f + __expf(-x));
}

// ---------------------------------------------------------------------------
// gemm_rows: one wave owns ONE 16-col tile (weights pre-offset by caller) and
// sweeps NSTR row-strips of 16. B-fragments batched in chunks; AS is a
// compile-time LDS row stride. FP order: ks ascending, lo-then-hi.
// ---------------------------------------------------------------------------
template<int KS, int NSTR, int AS>
__device__ __forceinline__ void gemm_rows(
    const u16* A,
    const u16* __restrict__ Wh, const u16* __restrict__ Wl,
    int lane, f4_t* acc)
{
    const int r = lane & 15;
    const int q = lane >> 4;
    const u16* ab = A + r * AS + q * 8;
    constexpr int CH = (KS > 4) ? 3 : KS;
#pragma unroll
    for (int c0 = 0; c0 < KS; c0 += CH) {
        bf8_t bh[CH], bl[CH];
#pragma unroll
        for (int j = 0; j < CH; ++j) {
            bh[j] = *(const bf8_t*)(Wh + ((c0 + j) * 64 + lane) * 8);
            bl[j] = *(const bf8_t*)(Wl + ((c0 + j) * 64 + lane) * 8);
        }
#pragma unroll
        for (int j = 0; j < CH; ++j) {
#pragma unroll
            for (int s = 0; s < NSTR; ++s) {
                bf8_t a = *(const bf8_t*)(ab + s * 16 * AS + (c0 + j) * 32);
                acc[s] = MFMA16(a, bl[j], acc[s], 0, 0, 0);
                acc[s] = MFMA16(a, bh[j], acc[s], 0, 0, 0);
            }
        }
    }
}

// ---------------------------------------------------------------------------
// gemm_swz: same as gemm_rows but A lives in a 16B-chunk XOR-swizzled LDS
// region of row stride ASW u16 (ASW multiple of 8; ASW*2 bytes = multiple of
// 128 -> rows alias banks, the XOR phys = chunk ^ (r&7) de-aliases).
// Logical A col chunk for (ks, q) = ks*4 + q. FP order identical.
// ---------------------------------------------------------------------------
template<int KS, int NSTR, int ASW>
__device__ __forceinline__ void gemm_swz(
    const u16* A,
    const u16* __restrict__ Wh, const u16* __restrict__ Wl,
    int lane, f4_t* acc)
{
    const int r = lane & 15;
    const int q = lane >> 4;
    const int r7 = r & 7;
    const u16* ab = A + r * ASW;
    constexpr int CH = (KS > 4) ? 3 : KS;
#pragma unroll
    for (int c0 = 0; c0 < KS; c0 += CH) {
        bf8_t bh[CH], bl[CH];
#pragma unroll
        for (int j = 0; j < CH; ++j) {
            bh[j] = *(const bf8_t*)(Wh + ((c0 + j) * 64 + lane) * 8);
            bl[j] = *(const bf8_t*)(Wl + ((c0 + j) * 64 + lane) * 8);
        }
#pragma unroll
        for (int j = 0; j < CH; ++j) {
            const int phys = (((c0 + j) * 4 + q) ^ r7) * 8;
#pragma unroll
            for (int s = 0; s < NSTR; ++s) {
                bf8_t a = *(const bf8_t*)(ab + s * 16 * ASW + phys);
                acc[s] = MFMA16(a, bl[j], acc[s], 0, 0, 0);
                acc[s] = MFMA16(a, bh[j], acc[s], 0, 0, 0);
            }
        }
    }
}

// ---------------------------------------------------------------------------
// Weight prep (+ fused edge histogram): fp32 [K][N] -> bf16 hi/lo in
// FRAGMENT-LINEAR layout: element ((tile*KS + ks)*64 + lane)*8 + j  holds
// W^T[col = tile*16 + (lane&15)][k = ks*32 + (lane>>4)*8 + j].
// ---------------------------------------------------------------------------
struct PD { const float* src; u16* hi; u16* lo; int K, N, Kp, perm, off, cnt; };
struct PDs { PD d[10]; };

__global__ __launch_bounds__(256) void prep_all(PDs P, int total,
                                                const int* __restrict__ eidx,
                                                int* __restrict__ cnt, int E)
{
    int i = blockIdx.x * 256 + threadIdx.x;
    if (i < E) atomicAdd(&cnt[eidx[i]], 1);
    if (i >= total) return;
#pragma unroll
    for (int rg = 0; rg < 10; ++rg) {
        if (i >= P.d[rg].off && i < P.d[rg].off + P.d[rg].cnt) {
            int li = i - P.d[rg].off;
            int KS = P.d[rg].Kp >> 5;
            int tile = li / (KS * 512);
            int rem  = li - tile * KS * 512;
            int ks   = rem >> 9;
            int lane = (rem >> 3) & 63;
            int j    = rem & 7;
            int n = tile * 16 + (lane & 15);
            int k = ks * 32 + (lane >> 4) * 8 + j;
            int ksrc = k;
            if (P.d[rg].perm && k >= 128)
                ksrc = (k < 160) ? (128 + 2 * (k - 128)) : (129 + 2 * (k - 160));
            float wv = (ksrc < P.d[rg].K) ? P.d[rg].src[(size_t)ksrc * P.d[rg].N + n] : 0.f;
            u16 h = f2bf(wv);
            P.d[rg].hi[li] = h;
            P.d[rg].lo[li] = f2bf(wv - bf2f(h));
        }
    }
}

// ---------------------------------------------------------------------------
// Exclusive scan over node counts (LDS-staged, coalesced).
// ---------------------------------------------------------------------------
__global__ __launch_bounds__(1024) void scan_k(const int* __restrict__ cnt,
                                               int* __restrict__ base,
                                               int* __restrict__ cursor, int NN)
{
    __shared__ int vals[12500];
    __shared__ int part[1024];
    const int t = threadIdx.x;
    for (int i = t; i < NN; i += 1024) vals[i] = cnt[i];
    __syncthreads();
    const int CHK = (NN + 1023) >> 10;
    const int lo = t * CHK, hi = min(lo + CHK, NN);
    int s = 0;
    for (int i = lo; i < hi; ++i) s += vals[i];
    part[t] = s;
    __syncthreads();
    for (int off = 1; off < 1024; off <<= 1) {
        int v = (t >= off) ? part[t - off] : 0;
        __syncthreads();
        part[t] += v;
        __syncthreads();
    }
    if (t == 0) base[NN] = part[1023];
    int run = (t == 0) ? 0 : part[t - 1];
    for (int i = lo; i < hi; ++i) { int c = vals[i]; vals[i] = run; run += c; }
    __syncthreads();
    for (int i = t; i < NN; i += 1024) { int v = vals[i]; base[i] = v; cursor[i] = v; }
}

__global__ __launch_bounds__(256) void scatter_k(const int* __restrict__ eidx,
                                                 int* __restrict__ cursor,
                                                 int* __restrict__ sorted, int E)
{
    int i = blockIdx.x * 256 + threadIdx.x;
    if (i < E) {
        int p = atomicAdd(&cursor[eidx[i]], 1);
        sorted[p] = i;
    }
}

// ---------------------------------------------------------------------------
// Segment reduction from WEIGHT-SPACE rows: env[node][c] =
//   SEG_NORM * sum_e  w[e][2m+(idx>0)] * attr[e][idx]   (c = 4m+idx).
// ---------------------------------------------------------------------------
__global__ __launch_bounds__(256) void reduce_env(
    const int* __restrict__ base, const int* __restrict__ sorted,
    const u16* __restrict__ envw, const float* __restrict__ attr,
    u16* __restrict__ env, int NN)
{
    const int node = blockIdx.x * 4 + (threadIdx.x >> 6);
    const int ch = threadIdx.x & 63;          // channel pair: 2ch, 2ch+1
    if (node >= NN) return;
    const int b = base[node], en = base[node + 1];
    const int wo = ch & ~1;                   // aligned u16 col of the u32 w-load
    const int ao = (ch & 1) * 2;              // attr index base
    const bool odd = (ch & 1) != 0;
    float a0 = 0.f, a1 = 0.f;
    int i = b;
    for (; i + 3 < en; i += 4) {
        int s0 = sorted[i], s1 = sorted[i + 1], s2 = sorted[i + 2], s3 = sorted[i + 3];
        u32 w0 = *(const u32*)(envw + (size_t)s0 * 64 + wo);
        u32 w1 = *(const u32*)(envw + (size_t)s1 * 64 + wo);
        u32 w2 = *(const u32*)(envw + (size_t)s2 * 64 + wo);
        u32 w3 = *(const u32*)(envw + (size_t)s3 * 64 + wo);
        float2 v0 = *(const float2*)(attr + (size_t)s0 * 4 + ao);
        float2 v1 = *(const float2*)(attr + (size_t)s1 * 4 + ao);
        float2 v2 = *(const float2*)(attr + (size_t)s2 * 4 + ao);
        float2 v3 = *(const float2*)(attr + (size_t)s3 * 4 + ao);
        float l0 = bf2f((u16)(odd ? (w0 >> 16) : w0)), h0 = bf2f((u16)(w0 >> 16));
        float l1 = bf2f((u16)(odd ? (w1 >> 16) : w1)), h1 = bf2f((u16)(w1 >> 16));
        float l2 = bf2f((u16)(odd ? (w2 >> 16) : w2)), h2 = bf2f((u16)(w2 >> 16));
        float l3 = bf2f((u16)(odd ? (w3 >> 16) : w3)), h3 = bf2f((u16)(w3 >> 16));
        a0 += (l0 * v0.x + l1 * v1.x) + (l2 * v2.x + l3 * v3.x);
        a1 += (h0 * v0.y + h1 * v1.y) + (h2 * v2.y + h3 * v3.y);
    }
    for (; i < en; ++i) {
        int s0 = sorted[i];
        u32 w0 = *(const u32*)(envw + (size_t)s0 * 64 + wo);
        float2 v0 = *(const float2*)(attr + (size_t)s0 * 4 + ao);
        a0 += bf2f((u16)(odd ? (w0 >> 16) : w0)) * v0.x;
        a1 += bf2f((u16)(w0 >> 16)) * v0.y;
    }
    *(u32*)(env + (size_t)node * 128 + 2 * ch) = cvtpk(a0 * SEG_NORM, a1 * SEG_NORM);
}

// ---------------------------------------------------------------------------
// Phase A. 8 waves; wave w owns col tile w (16 cols), sweeps all 64 rows.
// LDS 38912 <= 40960 -> 4 blocks/CU at (512,8).
// ---------------------------------------------------------------------------
__global__ __launch_bounds__(512, 8) void phaseA(
    const float* __restrict__ inv,
    const u16* __restrict__ Wh2b0, const u16* __restrict__ Wl2b0,
    const u16* __restrict__ Wh2b1, const u16* __restrict__ Wl2b1,
    const u16* __restrict__ Whenv0, const u16* __restrict__ Wlenv0,
    u16* __restrict__ latbuf, u16* __restrict__ featw,
    u16* __restrict__ envw, int E)
{
    __shared__ __align__(16) char sm[38912];
    u16 (*Xi)[32]  = (u16 (*)[32])sm;                     // 4096
    u16 (*Hs)[136] = (u16 (*)[136])(sm + 4096);           // 17408
    u16 (*Ls)[136] = (u16 (*)[136])(sm + 21504);          // 17408

    const int tid = threadIdx.x;
    const int lane = tid & 63;
    const int w = tid >> 6;
    const int e0 = blockIdx.x * 64;
    const int E1 = E - 1;
    const int r = lane & 15, q = lane >> 4;
    const bool full = (e0 + 64 <= E);

    // coalesced inv load: 64 rows x 8 floats contiguous (2KB)
    {
        int t = tid >> 3, c = tid & 7;
        Xi[t][c] = f2bf_hw(inv[(size_t)min(e0 + t, E1) * 8 + c]);
    }
    if (tid < 256) {                     // zero cols 8..31 (disjoint from loads)
        int t = tid >> 2, c = tid & 3;
        if (c) *(bf8_t*)&Xi[t][c * 8] = (bf8_t)(short)0;
    }
    __syncthreads();

    const f4_t z = {0.f, 0.f, 0.f, 0.f};
    f4_t acc[4];

    // GEMM1: inv(8->32) @ W2b0 -> silu -> Hs
#pragma unroll
    for (int s = 0; s < 4; ++s) acc[s] = z;
    gemm_rows<1, 4, 32>(&Xi[0][0], Wh2b0 + w * 512, Wl2b0 + w * 512, lane, acc);
#pragma unroll
    for (int s = 0; s < 4; ++s)
#pragma unroll
        for (int jj = 0; jj < 4; jj += 2) {
            u32 pk = cvtpk(silu_f(acc[s][jj] * RSQRT8), silu_f(acc[s][jj + 1] * RSQRT8));
            Hs[s * 16 + q * 4 + jj][w * 16 + r]     = (u16)pk;
            Hs[s * 16 + q * 4 + jj + 1][w * 16 + r] = (u16)(pk >> 16);
        }
    __syncthreads();

    // GEMM2: h(128) @ W2b1 -> lat -> Ls (latbuf written by bulk copy below)
#pragma unroll
    for (int s = 0; s < 4; ++s) acc[s] = z;
    gemm_rows<4, 4, 136>(&Hs[0][0], Wh2b1 + w * 4 * 512, Wl2b1 + w * 4 * 512, lane, acc);
#pragma unroll
    for (int s = 0; s < 4; ++s)
#pragma unroll
        for (int jj = 0; jj < 4; jj += 2) {
            int row0 = s * 16 + q * 4 + jj, cc = w * 16 + r;
            u32 pk = cvtpk(acc[s][jj] * RSQRT128, acc[s][jj + 1] * RSQRT128);
            Ls[row0][cc]     = (u16)pk;
            Ls[row0 + 1][cc] = (u16)(pk >> 16);
        }
    __syncthreads();

    // coalesced Ls -> latbuf (overlaps with GEMM3's MFMA work)
    for (int i = tid; i < 1024; i += 512) {
        int t = i >> 4, c = i & 15;
        int e = e0 + t;
        if (full || e < E)
            *(bf8_t*)(latbuf + (size_t)e * 128 + c * 8) = *(const bf8_t*)&Ls[t][c * 8];
    }

    // GEMM3: lat(128) @ Wenv0 -> w0; stage into Hs (dead), bulk-copy out.
#pragma unroll
    for (int s = 0; s < 4; ++s) acc[s] = z;
    gemm_rows<4, 4, 136>(&Ls[0][0], Whenv0 + w * 4 * 512, Wlenv0 + w * 4 * 512, lane, acc);
    {
        const int col = w * 16 + r;
#pragma unroll
        for (int s = 0; s < 4; ++s)
#pragma unroll
            for (int jj = 0; jj < 4; jj += 2) {
                int row0 = s * 16 + q * 4 + jj;
                u32 pk = cvtpk(acc[s][jj] * RSQRT128, acc[s][jj + 1] * RSQRT128);
                Hs[row0][col]     = (u16)pk;
                Hs[row0 + 1][col] = (u16)(pk >> 16);
            }
    }
    __syncthreads();
    for (int i = tid; i < 1024; i += 512) {
        int t = i >> 4, c = i & 15;
        int e = e0 + t;
        if (full || e < E) {
            u16* dst = (c < 8) ? (featw + (size_t)e * 64 + c * 8)
                               : (envw + (size_t)e * 64 + (c - 8) * 8);
            *(bf8_t*)dst = *(const bf8_t*)&Hs[t][c * 8];
        }
    }
}

// ---------------------------------------------------------------------------
// Phase B: unchanged structure from R5 (3 blocks/CU; P-removal held in
// reserve pending R6's occupancy read on phaseC).
// ---------------------------------------------------------------------------
__global__ __launch_bounds__(512, 6) void phaseB(
    const int* __restrict__ eidx, const float* __restrict__ attr,
    const u16* __restrict__ env0b,
    const u16* __restrict__ featw, u16* __restrict__ envw,
    const u16* __restrict__ Whs0, const u16* __restrict__ Wls0,
    const u16* __restrict__ Whv0, const u16* __restrict__ Wlv0,
    const u16* __restrict__ Whl10, const u16* __restrict__ Wll10,
    const u16* __restrict__ Whl11, const u16* __restrict__ Wll11,
    const u16* __restrict__ Whe1, const u16* __restrict__ Wle1,
    u16* __restrict__ latbuf, u16* __restrict__ featbuf, int E)
{
    __shared__ __align__(16) char sm[51200];
    u16 (*X4)[200] = (u16 (*)[200])sm;                    // 25600: lat|ss|vv -> lat2
    u16 (*P)[200]  = (u16 (*)[200])(sm + 25600);          // 25600: sv|vs per dim (192 used)
    u16 (*Hs)[136] = (u16 (*)[136])(sm + 25600);          // overlay P (dead post-mix)

    const int tid = threadIdx.x;
    const int lane = tid & 63;
    const int w = tid >> 6;
    const int e0 = blockIdx.x * 64;
    const int E1 = E - 1;
    const int r = lane & 15, q = lane >> 4;
    const bool full = (e0 + 64 <= E);

    // lat -> X4[:, 0:128]
    for (int i = tid; i < 64 * 16; i += 512) {
        int t = i >> 4, dc = i & 15;
        *(bf8_t*)&X4[t][dc * 8] = ((const bf8_t*)(latbuf + (size_t)min(e0 + t, E1) * 128))[dc];
    }

    // tensor-product pass: f-channels reconstructed from w0 row x attr.
    {
        const int t = tid >> 3, cg = tid & 7;
        const int e = min(e0 + t, E1);
        const int nd = eidx[e];
        bf8_t wv = *(const bf8_t*)(featw + (size_t)e * 64 + cg * 8);
        const u16* gp = env0b + (size_t)nd * 128 + cg * 16;
        bf8_t gA = *(const bf8_t*)gp;
        bf8_t gB = *(const bf8_t*)(gp + 8);
        float4 av = *(const float4*)(attr + (size_t)e * 4);
        float ssf[4], vvf[4], svf[3][4], vsf[3][4];
#pragma unroll
        for (int c = 0; c < 4; ++c) {
            float wf0 = bf2f((u16)wv[2 * c]);
            float wf1 = bf2f((u16)wv[2 * c + 1]);
            float f0 = wf0 * av.x, f1 = wf1 * av.y, f2 = wf1 * av.z, f3 = wf1 * av.w;
            float g0, g1, g2, g3;
            if (c < 2) {
                g0 = bf2f((u16)gA[4 * c]);     g1 = bf2f((u16)gA[4 * c + 1]);
                g2 = bf2f((u16)gA[4 * c + 2]); g3 = bf2f((u16)gA[4 * c + 3]);
            } else {
                int cc = c - 2;
                g0 = bf2f((u16)gB[4 * cc]);     g1 = bf2f((u16)gB[4 * cc + 1]);
                g2 = bf2f((u16)gB[4 * cc + 2]); g3 = bf2f((u16)gB[4 * cc + 3]);
            }
            ssf[c] = f0 * g0;
            vvf[c] = (f1 * g1 + f2 * g2 + f3 * g3) * INV_SQRT3;
            svf[0][c] = f0 * g1;  svf[1][c] = f0 * g2;  svf[2][c] = f0 * g3;
            vsf[0][c] = f1 * g0;  vsf[1][c] = f2 * g0;  vsf[2][c] = f3 * g0;
        }
        *(uint2*)&X4[t][128 + 4 * cg] = make_uint2(cvtpk(ssf[0], ssf[1]), cvtpk(ssf[2], ssf[3]));
        *(uint2*)&X4[t][160 + 4 * cg] = make_uint2(cvtpk(vvf[0], vvf[1]), cvtpk(vvf[2], vvf[3]));
#pragma unroll
        for (int d = 0; d < 3; ++d) {
            *(uint2*)&P[t][d * 64 + 4 * cg]      = make_uint2(cvtpk(svf[d][0], svf[d][1]), cvtpk(svf[d][2], svf[d][3]));
            *(uint2*)&P[t][d * 64 + 32 + 4 * cg] = make_uint2(cvtpk(vsf[d][0], vsf[d][1]), cvtpk(vsf[d][2], vsf[d][3]));
        }
    }
    __syncthreads();

    const f4_t z = {0.f, 0.f, 0.f, 0.f};

    // ---- mix: wave = (strip sw, col-half cw); B-frags loaded once, shared
    // across S and all 3 V dims.
    {
        const int sw = w >> 1, cw = w & 1;
        f4_t aS = z, aV[3] = {z, z, z};
        const u16* bsh = Whs0 + cw * 2 * 512;
        const u16* bsl = Wls0 + cw * 2 * 512;
        const u16* bvh = Whv0 + cw * 2 * 512;
        const u16* bvl = Wlv0 + cw * 2 * 512;
        bf8_t s0h = *(const bf8_t*)(bsh + lane * 8);
        bf8_t s0l = *(const bf8_t*)(bsl + lane * 8);
        bf8_t s1h = *(const bf8_t*)(bsh + 512 + lane * 8);
        bf8_t s1l = *(const bf8_t*)(bsl + 512 + lane * 8);
        bf8_t v0h = *(const bf8_t*)(bvh + lane * 8);
        bf8_t v0l = *(const bf8_t*)(bvl + lane * 8);
        bf8_t v1h = *(const bf8_t*)(bvh + 512 + lane * 8);
        bf8_t v1l = *(const bf8_t*)(bvl + 512 + lane * 8);
        const u16* arow = &X4[sw * 16 + r][0];
        bf8_t a0 = *(const bf8_t*)(arow + 128 + q * 8);
        bf8_t a1 = *(const bf8_t*)(arow + 160 + q * 8);
        aS = MFMA16(a0, s0l, aS, 0, 0, 0);
        aS = MFMA16(a0, s0h, aS, 0, 0, 0);
        aS = MFMA16(a1, s1l, aS, 0, 0, 0);
        aS = MFMA16(a1, s1h, aS, 0, 0, 0);
        const u16* prow = &P[sw * 16 + r][0];
#pragma unroll
        for (int d = 0; d < 3; ++d) {
            bf8_t p0 = *(const bf8_t*)(prow + d * 64 + q * 8);
            bf8_t p1 = *(const bf8_t*)(prow + d * 64 + 32 + q * 8);
            aV[d] = MFMA16(p0, v0l, aV[d], 0, 0, 0);
            aV[d] = MFMA16(p0, v0h, aV[d], 0, 0, 0);
            aV[d] = MFMA16(p1, v1l, aV[d], 0, 0, 0);
            aV[d] = MFMA16(p1, v1h, aV[d], 0, 0, 0);
        }
        // feat2 direct to global: one 8B store per reg (128B/16-lane group)
        const int m = cw * 16 + r;
#pragma unroll
        for (int reg = 0; reg < 4; ++reg) {
            int e = e0 + sw * 16 + q * 4 + reg;
            if (full || e < E) {
                uint2 pv;
                pv.x = cvtpk(aS[reg] * RSQRT64,
                             aV[0][reg] * (RSQRT64 * INV_SQRT3));
                pv.y = cvtpk(aV[1][reg] * (RSQRT64 * INV_SQRT3),
                             aV[2][reg] * (RSQRT64 * INV_SQRT3));
                *(uint2*)(featbuf + (size_t)e * 128 + 4 * m) = pv;
            }
        }
    }

    // GEMM4: [lat|sscal](192) @ Wlat1_0
    f4_t acc[4];
#pragma unroll
    for (int s = 0; s < 4; ++s) acc[s] = z;
    gemm_rows<6, 4, 200>(&X4[0][0], Whl10 + w * 6 * 512, Wll10 + w * 6 * 512, lane, acc);
    __syncthreads();   // all P reads (mix) done -> Hs may overwrite P
#pragma unroll
    for (int s = 0; s < 4; ++s)
#pragma unroll
        for (int jj = 0; jj < 4; jj += 2) {
            u32 pk = cvtpk(silu_f(acc[s][jj] * RSQRT192), silu_f(acc[s][jj + 1] * RSQRT192));
            Hs[s * 16 + q * 4 + jj][w * 16 + r]     = (u16)pk;
            Hs[s * 16 + q * 4 + jj + 1][w * 16 + r] = (u16)(pk >> 16);
        }
    __syncthreads();

    // GEMM5: h @ Wlat1_1 -> new_lat; lat2 = C*(lat+new_lat) in place in X4
#pragma unroll
    for (int s = 0; s < 4; ++s) acc[s] = z;
    gemm_rows<4, 4, 136>(&Hs[0][0], Whl11 + w * 4 * 512, Wll11 + w * 4 * 512, lane, acc);
#pragma unroll
    for (int s = 0; s < 4; ++s)
#pragma unroll
        for (int jj = 0; jj < 4; jj += 2) {
            int row0 = s * 16 + q * 4 + jj, cc = w * 16 + r;
            float l2a = C_HALF * (bf2f(X4[row0][cc]) + acc[s][jj] * RSQRT128);
            float l2b = C_HALF * (bf2f(X4[row0 + 1][cc]) + acc[s][jj + 1] * RSQRT128);
            u32 pk = cvtpk(l2a, l2b);
            X4[row0][cc]     = (u16)pk;       // cells owned by this lane-reg only
            X4[row0 + 1][cc] = (u16)(pk >> 16);
        }
    __syncthreads();

    // lat2 -> latbuf (coalesced) ; GEMM6: lat2 @ Wenv1 -> w1 staged in X4
    for (int i = tid; i < 64 * 16; i += 512) {
        int t = i >> 4, dc = i & 15;
        int e = e0 + t;
        if (full || e < E)
            ((bf8_t*)(latbuf + (size_t)e * 128))[dc] = *(const bf8_t*)&X4[t][dc * 8];
    }
    {
        const int ct = w & 3, rh = w >> 2;   // col tile 0..3, row half 0..1
        f4_t a6[2] = {z, z};
        gemm_rows<4, 2, 200>(&X4[rh * 32][0], Whe1 + ct * 4 * 512, Wle1 + ct * 4 * 512, lane, a6);
        const int col = ct * 16 + r;         // 0..63
#pragma unroll
        for (int s = 0; s < 2; ++s)
#pragma unroll
            for (int jj = 0; jj < 4; jj += 2) {
                int row0 = rh * 32 + s * 16 + q * 4 + jj;
                u32 pk = cvtpk(a6[s][jj] * RSQRT128, a6[s][jj + 1] * RSQRT128);
                X4[row0][128 + col]     = (u16)pk;     // stage (cols 128.. dead)
                X4[row0 + 1][128 + col] = (u16)(pk >> 16);
            }
    }
    __syncthreads();
    // coalesced w1 copy: 64 rows x 64 u16 = 512 chunks of 16B
    {
        int t = tid >> 3, c = tid & 7;
        int e = e0 + t;
        if (full || e < E)
            *(bf8_t*)(envw + (size_t)e * 64 + c * 8) = *(const bf8_t*)&X4[t][128 + c * 8];
    }
}

// ---------------------------------------------------------------------------
// Phase C: swizzled LDS (X7 stride 192, Hs stride 128; 16B-chunk XOR by
// row&7) -> 40960 B -> 4 blocks/CU at (512,8).
// ---------------------------------------------------------------------------
__global__ __launch_bounds__(512, 8) void phaseC(
    const int* __restrict__ eidx, const u16* __restrict__ env1b,
    const u16* __restrict__ Whf0, const u16* __restrict__ Wlf0,
    const u16* __restrict__ Whf1, const u16* __restrict__ Wlf1,
    const u16* __restrict__ latbuf, const u16* __restrict__ featbuf,
    float* __restrict__ outp, int E)
{
    __shared__ __align__(16) u16 smX[64 * 192];           // 24576 B
    __shared__ __align__(16) u16 smH[64 * 128];           // 16384 B

    const int tid = threadIdx.x;
    const int lane = tid & 63;
    const int w = tid >> 6;
    const int e0 = blockIdx.x * 64;
    const int E1 = E - 1;
    const int r = lane & 15, q = lane >> 4;
    const int r7 = r & 7;
    const bool full = (e0 + 64 <= E);

    // lat2 -> smX chunks 0..15 (swizzled)
    for (int i = tid; i < 64 * 16; i += 512) {
        int t = i >> 4, dc = i & 15;
        *(bf8_t*)(smX + t * 192 + ((dc ^ (t & 7)) * 8)) =
            ((const bf8_t*)(latbuf + (size_t)min(e0 + t, E1) * 128))[dc];
    }

    // scalars1 pass: ss/vv -> smX chunks 16..23 (swizzled)
    {
        const int t = tid >> 3, cg = tid & 7;
        const int e = min(e0 + t, E1);
        const int nd = eidx[e];
        const u16* fp = featbuf + (size_t)e * 128 + cg * 16;
        const u16* gp = env1b + (size_t)nd * 128 + cg * 16;
        bf8_t fA = *(const bf8_t*)fp;
        bf8_t fB = *(const bf8_t*)(fp + 8);
        bf8_t gA = *(const bf8_t*)gp;
        bf8_t gB = *(const bf8_t*)(gp + 8);
        float ssf[4], vvf[4];
#pragma unroll
        for (int c = 0; c < 4; ++c) {
            float f0, f1, f2, f3, g0, g1, g2, g3;
            if (c < 2) {
                f0 = bf2f((u16)fA[4 * c]);     g0 = bf2f((u16)gA[4 * c]);
                f1 = bf2f((u16)fA[4 * c + 1]); g1 = bf2f((u16)gA[4 * c + 1]);
                f2 = bf2f((u16)fA[4 * c + 2]); g2 = bf2f((u16)gA[4 * c + 2]);
                f3 = bf2f((u16)fA[4 * c + 3]); g3 = bf2f((u16)gA[4 * c + 3]);
            } else {
                int cc = c - 2;
                f0 = bf2f((u16)fB[4 * cc]);     g0 = bf2f((u16)gB[4 * cc]);
                f1 = bf2f((u16)fB[4 * cc + 1]); g1 = bf2f((u16)gB[4 * cc + 1]);
                f2 = bf2f((u16)fB[4 * cc + 2]); g2 = bf2f((u16)gB[4 * cc + 2]);
                f3 = bf2f((u16)fB[4 * cc + 3]); g3 = bf2f((u16)gB[4 * cc + 3]);
            }
            ssf[c] = f0 * g0;
            vvf[c] = (f1 * g1 + f2 * g2 + f3 * g3) * INV_SQRT3;
        }
        const int t7 = t & 7;
        const int half = (cg & 1) * 4;                  // u16 offset in chunk
        u16* px = smX + t * 192;
        *(uint2*)(px + ((16 + (cg >> 1)) ^ t7) * 8 + half) =
            make_uint2(cvtpk(ssf[0], ssf[1]), cvtpk(ssf[2], ssf[3]));
        *(uint2*)(px + ((20 + (cg >> 1)) ^ t7) * 8 + half) =
            make_uint2(cvtpk(vvf[0], vvf[1]), cvtpk(vvf[2], vvf[3]));
    }
    __syncthreads();

    const f4_t z = {0.f, 0.f, 0.f, 0.f};
    f4_t acc[4];
#pragma unroll
    for (int s = 0; s < 4; ++s) acc[s] = z;
    gemm_swz<6, 4, 192>(smX, Whf0 + w * 6 * 512, Wlf0 + w * 6 * 512, lane, acc);
    // smH is a disjoint region -> no barrier needed before the writes
    {
        const int hc = 2 * w + (r >> 3);                // chunk of col w*16+r
#pragma unroll
        for (int s = 0; s < 4; ++s)
#pragma unroll
            for (int jj = 0; jj < 4; jj += 2) {
                int row0 = s * 16 + q * 4 + jj;
                u32 pk = cvtpk(silu_f(acc[s][jj] * RSQRT192), silu_f(acc[s][jj + 1] * RSQRT192));
                smH[row0 * 128 + ((hc ^ (row0 & 7)) * 8) + r7]             = (u16)pk;
                smH[(row0 + 1) * 128 + ((hc ^ ((row0 + 1) & 7)) * 8) + r7] = (u16)(pk >> 16);
            }
    }
    __syncthreads();

#pragma unroll
    for (int s = 0; s < 4; ++s) acc[s] = z;
    gemm_swz<4, 4, 128>(smH, Whf1 + w * 4 * 512, Wlf1 + w * 4 * 512, lane, acc);
    {
        const int xc = 2 * w + (r >> 3);                // chunk of col w*16+r
#pragma unroll
        for (int s = 0; s < 4; ++s)
#pragma unroll
            for (int jj = 0; jj < 4; ++jj) {
                int row = s * 16 + q * 4 + jj;
                int e = e0 + row;
                if (full || e < E) {
                    u16 l2 = smX[row * 192 + ((xc ^ (row & 7)) * 8) + r7];
                    outp[(size_t)e * 128 + w * 16 + r] =
                        SQ23 * bf2f(l2) + SQ13 * (acc[s][jj] * RSQRT128);
                }
            }
    }
}

extern "C" void kernel_launch(void* const* d_in, const int* in_sizes, int n_in,
                              void* d_out, int out_size, void* d_ws, size_t ws_size,
                              hipStream_t stream)
{
    const int E  = in_sizes[0] / 2;
    const int NN = 12500;

    const int*   eidx    = (const int*)d_in[0];
    const float* attr    = (const float*)d_in[1];
    const float* inv     = (const float*)d_in[2];
    float* outp = (float*)d_out;

    // ws: lat bf16 | feat2 bf16 | env0b, env1b bf16 | weights | sort ints
    u16* latbuf  = (u16*)d_ws;
    u16* featbuf = latbuf + (size_t)E * 128;
    u16* env0b   = featbuf + (size_t)E * 128;
    u16* env1b   = env0b + (size_t)NN * 128;
    u16* p = env1b + (size_t)NN * 128;
    auto carve = [&](int elems) { u16* q0 = p; p += elems; return q0; };
    u16 *Wh2b0 = carve(128 * 32),  *Wl2b0 = carve(128 * 32);
    u16 *Wh2b1 = carve(128 * 128), *Wl2b1 = carve(128 * 128);
    u16 *Whe0  = carve(128 * 128), *Wle0  = carve(128 * 128);
    u16 *Whl10 = carve(128 * 192), *Wll10 = carve(128 * 192);
    u16 *Whl11 = carve(128 * 128), *Wll11 = carve(128 * 128);
    u16 *Whe1  = carve(64 * 128),  *Wle1  = carve(64 * 128);
    u16 *Whs0  = carve(32 * 64),   *Wls0  = carve(32 * 64);
    u16 *Whv0  = carve(32 * 64),   *Wlv0  = carve(32 * 64);
    u16 *Whf0  = carve(128 * 192), *Wlf0  = carve(128 * 192);
    u16 *Whf1  = carve(128 * 128), *Wlf1  = carve(128 * 128);
    int* cnt;
    {
        size_t off_bytes = (size_t)((char*)p - (char*)d_ws);
        off_bytes = (off_bytes + 3) & ~(size_t)3;
        cnt = (int*)((char*)d_ws + off_bytes);
    }
    int* base   = cnt + NN;          // NN+1 entries
    int* cursor = base + NN + 1;
    int* sorted = cursor + NN;

    // w-space scratch lives in d_out (fully overwritten by phaseC afterwards):
    // featw = w0[:, :64] rows, envw = w0[:,64:] rows then w1 rows.
    u16* featw = (u16*)d_out;
    u16* envw  = featw + (size_t)E * 64;

    hipMemsetAsync(cnt, 0, NN * sizeof(int), stream);

    // ---- weight prep + edge histogram (one kernel) ----
    PDs P;
    auto setpd = [&](int i, const float* s, u16* h, u16* l, int K, int N, int Kp, int pm, int off) {
        P.d[i] = {s, h, l, K, N, Kp, pm, off, N * Kp};
    };
    setpd(0, (const float*)d_in[3],  Wh2b0, Wl2b0,   8, 128,  32, 0, 0);
    setpd(1, (const float*)d_in[4],  Wh2b1, Wl2b1, 128, 128, 128, 0, 4096);
    setpd(2, (const float*)d_in[5],  Whe0,  Wle0,  128, 128, 128, 0, 20480);
    setpd(3, (const float*)d_in[6],  Whl10, Wll10, 192, 128, 192, 1, 36864);
    setpd(4, (const float*)d_in[7],  Whl11, Wll11, 128, 128, 128, 0, 61440);
    setpd(5, (const float*)d_in[8],  Whe1,  Wle1,  128,  64, 128, 0, 77824);
    setpd(6, (const float*)d_in[9],  Whs0,  Wls0,   64,  32,  64, 0, 86016);
    setpd(7, (const float*)d_in[10], Whv0,  Wlv0,   64,  32,  64, 0, 88064);
    setpd(8, (const float*)d_in[11], Whf0,  Wlf0,  192, 128, 192, 1, 90112);
    setpd(9, (const float*)d_in[12], Whf1,  Wlf1,  128, 128, 128, 0, 114688);
    const int total = 131072;
    const int span = (E > total) ? E : total;
    prep_all<<<(span + 255) / 256, 256, 0, stream>>>(P, total, eidx, cnt, E);

    // ---- counting sort of edges by center node ----
    scan_k<<<1, 1024, 0, stream>>>(cnt, base, cursor, NN);
    scatter_k<<<(E + 255) / 256, 256, 0, stream>>>(eidx, cursor, sorted, E);

    const int nb = (E + 63) / 64;
    phaseA<<<nb, 512, 0, stream>>>(inv, Wh2b0, Wl2b0, Wh2b1, Wl2b1,
                                   Whe0, Wle0, latbuf, featw, envw, E);
    reduce_env<<<(NN + 3) / 4, 256, 0, stream>>>(base, sorted, envw, attr, env0b, NN);
    phaseB<<<nb, 512, 0, stream>>>(eidx, attr, env0b, featw, envw,
                                   Whs0, Wls0, Whv0, Wlv0,
                                   Whl10, Wll10, Whl11, Wll11, Whe1, Wle1,
                                   latbuf, featbuf, E);
    reduce_env<<<(NN + 3) / 4, 256, 0, stream>>>(base, sorted, envw, attr, env1b, NN);
    phaseC<<<nb, 512, 0, stream>>>(eidx, env1b, Whf0, Wlf0, Whf1, Wlf1,
                                   latbuf, featbuf, outp, E);
}

// Round 8
// 353.478 us; speedup vs baseline: 1.0061x; 1.0061x over previous
//
#include <hip/hip_runtime.h>

typedef __attribute__((ext_vector_type(8))) short bf8_t;   // 8 x bf16 (4 VGPRs)
typedef __attribute__((ext_vector_type(4))) short bf4_t;   // 4 x bf16 (2 VGPRs)
typedef __attribute__((ext_vector_type(4))) float f4_t;    // 4 x fp32 acc
typedef unsigned short u16;
typedef unsigned int u32;

#define MFMA16 __builtin_amdgcn_mfma_f32_16x16x32_bf16

#define RSQRT8    0.35355339059327373f
#define RSQRT128  0.08838834764831845f
#define RSQRT192  0.07216878364870323f
#define RSQRT64   0.125f
#define INV_SQRT3 0.57735026918962576f
#define SEG_NORM  0.25f       /* 1/sqrt(16) */
#define C_HALF    0.70710678118654752f
#define SQ23      0.81649658092772603f
#define SQ13      0.57735026918962576f

__device__ __forceinline__ float bf2f(u16 b) {
    return __uint_as_float(((u32)b) << 16);
}
// software RNE (cold paths only; bit-identical to HW cvt)
__device__ __forceinline__ u16 f2bf(float f) {
    u32 u = __float_as_uint(f);
    u += 0x7FFFu + ((u >> 16) & 1u);
    return (u16)(u >> 16);
}
// hardware RNE pack: lo -> bits[15:0], hi -> bits[31:16]; 1 VALU inst
__device__ __forceinline__ u32 cvtpk(float lo, float hi) {
    u32 r;
    asm("v_cvt_pk_bf16_f32 %0, %1, %2" : "=v"(r) : "v"(lo), "v"(hi));
    return r;
}
__device__ __forceinline__ u16 f2bf_hw(float f) { return (u16)cvtpk(f, f); }
__device__ __forceinline__ float silu_f(float x) {
    return x * __builtin_amdgcn_rcpf(1.0f + __expf(-x));
}

// ---------------------------------------------------------------------------
// gemm_rows: one wave owns ONE 16-col tile (weights pre-offset by caller) and
// sweeps NSTR row-strips of 16. B-fragments batched in chunks; AS is a
// compile-time LDS row stride. FP order: ks ascending, lo-then-hi.
// ---------------------------------------------------------------------------
template<int KS, int NSTR, int AS>
__device__ __forceinline__ void gemm_rows(
    const u16* A,
    const u16* __restrict__ Wh, const u16* __restrict__ Wl,
    int lane, f4_t* acc)
{
    const int r = lane & 15;
    const int q = lane >> 4;
    const u16* ab = A + r * AS + q * 8;
    constexpr int CH = (KS > 4) ? 3 : KS;
#pragma unroll
    for (int c0 = 0; c0 < KS; c0 += CH) {
        bf8_t bh[CH], bl[CH];
#pragma unroll
        for (int j = 0; j < CH; ++j) {
            bh[j] = *(const bf8_t*)(Wh + ((c0 + j) * 64 + lane) * 8);
            bl[j] = *(const bf8_t*)(Wl + ((c0 + j) * 64 + lane) * 8);
        }
#pragma unroll
        for (int j = 0; j < CH; ++j) {
#pragma unroll
            for (int s = 0; s < NSTR; ++s) {
                bf8_t a = *(const bf8_t*)(ab + s * 16 * AS + (c0 + j) * 32);
                acc[s] = MFMA16(a, bl[j], acc[s], 0, 0, 0);
                acc[s] = MFMA16(a, bh[j], acc[s], 0, 0, 0);
            }
        }
    }
}

// ---------------------------------------------------------------------------
// Weight prep (+ fused edge histogram), SOURCE-LINEAR: thread i reads one
// contiguous fp32 source element (coalesced 256B/wave; the old dest-linear
// version read at stride N*4B = isolated 4B lines, latency-serialized) and
// scatters the bf16 hi/lo pair to the fragment-linear destination:
// dest = ((tile*KS + ks)*64 + q*16 + r)*8 + j  for col n, k-row k, where
// tile=n>>4, r=n&15, ks=k>>5, q=(k>>3)&3, j=k&7. perm regions invert the
// k-permutation (src row sk>=128: k = sk odd ? 160+(sk-129)/2 : 128+(sk-128)/2).
// Region 0 (K=8 -> Kp=32) zero-pad handled by tail range [128000,131072).
// ---------------------------------------------------------------------------
struct PD { const float* src; u16* hi; u16* lo; int Nsh, Kp, perm, off, cnt; };
struct PDs { PD d[10]; };

__global__ __launch_bounds__(256) void prep_all(PDs P, int total,
                                                const int* __restrict__ eidx,
                                                int* __restrict__ cnt, int E)
{
    int i = blockIdx.x * 256 + threadIdx.x;
    if (i < E) atomicAdd(&cnt[eidx[i]], 1);
    if (i >= total + 3072) return;
    if (i >= total) {                     // region-0 pad: k in [8,32), all n
        int p = i - total;
        int n = p & 127, kk = 8 + (p >> 7);
        int dest = (((n >> 4) + (kk >> 5)) * 64 + ((kk >> 3) & 3) * 16 + (n & 15)) * 8 + (kk & 7);
        P.d[0].hi[dest] = 0;
        P.d[0].lo[dest] = 0;
        return;
    }
#pragma unroll
    for (int rg = 0; rg < 10; ++rg) {
        if (i >= P.d[rg].off && i < P.d[rg].off + P.d[rg].cnt) {
            int li = i - P.d[rg].off;
            int sk = li >> P.d[rg].Nsh;
            int n  = li & ((1 << P.d[rg].Nsh) - 1);
            float wv = P.d[rg].src[li];
            int k = sk;
            if (P.d[rg].perm && sk >= 128)
                k = (sk & 1) ? (160 + ((sk - 129) >> 1)) : (128 + ((sk - 128) >> 1));
            int KS = P.d[rg].Kp >> 5;
            int dest = (((n >> 4) * KS + (k >> 5)) * 64 + ((k >> 3) & 3) * 16 + (n & 15)) * 8 + (k & 7);
            u16 h = f2bf(wv);
            P.d[rg].hi[dest] = h;
            P.d[rg].lo[dest] = f2bf(wv - bf2f(h));
        }
    }
}

// ---------------------------------------------------------------------------
// Exclusive scan over node counts (LDS-staged, coalesced).
// ---------------------------------------------------------------------------
__global__ __launch_bounds__(1024) void scan_k(const int* __restrict__ cnt,
                                               int* __restrict__ base,
                                               int* __restrict__ cursor, int NN)
{
    __shared__ int vals[12500];
    __shared__ int part[1024];
    const int t = threadIdx.x;
    for (int i = t; i < NN; i += 1024) vals[i] = cnt[i];
    __syncthreads();
    const int CHK = (NN + 1023) >> 10;
    const int lo = t * CHK, hi = min(lo + CHK, NN);
    int s = 0;
    for (int i = lo; i < hi; ++i) s += vals[i];
    part[t] = s;
    __syncthreads();
    for (int off = 1; off < 1024; off <<= 1) {
        int v = (t >= off) ? part[t - off] : 0;
        __syncthreads();
        part[t] += v;
        __syncthreads();
    }
    if (t == 0) base[NN] = part[1023];
    int run = (t == 0) ? 0 : part[t - 1];
    for (int i = lo; i < hi; ++i) { int c = vals[i]; vals[i] = run; run += c; }
    __syncthreads();
    for (int i = t; i < NN; i += 1024) { int v = vals[i]; base[i] = v; cursor[i] = v; }
}

__global__ __launch_bounds__(256) void scatter_k(const int* __restrict__ eidx,
                                                 int* __restrict__ cursor,
                                                 int* __restrict__ sorted, int E)
{
    int i = blockIdx.x * 256 + threadIdx.x;
    if (i < E) {
        int p = atomicAdd(&cursor[eidx[i]], 1);
        sorted[p] = i;
    }
}

// ---------------------------------------------------------------------------
// Segment reduction from WEIGHT-SPACE rows: env[node][c] =
//   SEG_NORM * sum_e  w[e][2m+(idx>0)] * attr[e][idx]   (c = 4m+idx).
// ---------------------------------------------------------------------------
__global__ __launch_bounds__(256) void reduce_env(
    const int* __restrict__ base, const int* __restrict__ sorted,
    const u16* __restrict__ envw, const float* __restrict__ attr,
    u16* __restrict__ env, int NN)
{
    const int node = blockIdx.x * 4 + (threadIdx.x >> 6);
    const int ch = threadIdx.x & 63;          // channel pair: 2ch, 2ch+1
    if (node >= NN) return;
    const int b = base[node], en = base[node + 1];
    const int wo = ch & ~1;                   // aligned u16 col of the u32 w-load
    const int ao = (ch & 1) * 2;              // attr index base
    const bool odd = (ch & 1) != 0;
    float a0 = 0.f, a1 = 0.f;
    int i = b;
    for (; i + 3 < en; i += 4) {
        int s0 = sorted[i], s1 = sorted[i + 1], s2 = sorted[i + 2], s3 = sorted[i + 3];
        u32 w0 = *(const u32*)(envw + (size_t)s0 * 64 + wo);
        u32 w1 = *(const u32*)(envw + (size_t)s1 * 64 + wo);
        u32 w2 = *(const u32*)(envw + (size_t)s2 * 64 + wo);
        u32 w3 = *(const u32*)(envw + (size_t)s3 * 64 + wo);
        float2 v0 = *(const float2*)(attr + (size_t)s0 * 4 + ao);
        float2 v1 = *(const float2*)(attr + (size_t)s1 * 4 + ao);
        float2 v2 = *(const float2*)(attr + (size_t)s2 * 4 + ao);
        float2 v3 = *(const float2*)(attr + (size_t)s3 * 4 + ao);
        float l0 = bf2f((u16)(odd ? (w0 >> 16) : w0)), h0 = bf2f((u16)(w0 >> 16));
        float l1 = bf2f((u16)(odd ? (w1 >> 16) : w1)), h1 = bf2f((u16)(w1 >> 16));
        float l2 = bf2f((u16)(odd ? (w2 >> 16) : w2)), h2 = bf2f((u16)(w2 >> 16));
        float l3 = bf2f((u16)(odd ? (w3 >> 16) : w3)), h3 = bf2f((u16)(w3 >> 16));
        a0 += (l0 * v0.x + l1 * v1.x) + (l2 * v2.x + l3 * v3.x);
        a1 += (h0 * v0.y + h1 * v1.y) + (h2 * v2.y + h3 * v3.y);
    }
    for (; i < en; ++i) {
        int s0 = sorted[i];
        u32 w0 = *(const u32*)(envw + (size_t)s0 * 64 + wo);
        float2 v0 = *(const float2*)(attr + (size_t)s0 * 4 + ao);
        a0 += bf2f((u16)(odd ? (w0 >> 16) : w0)) * v0.x;
        a1 += bf2f((u16)(w0 >> 16)) * v0.y;
    }
    *(u32*)(env + (size_t)node * 128 + 2 * ch) = cvtpk(a0 * SEG_NORM, a1 * SEG_NORM);
}

// ---------------------------------------------------------------------------
// Phase A (R5 version). 8 waves; wave w owns col tile w, sweeps all 64 rows.
// ---------------------------------------------------------------------------
__global__ __launch_bounds__(512, 6) void phaseA(
    const float* __restrict__ inv,
    const u16* __restrict__ Wh2b0, const u16* __restrict__ Wl2b0,
    const u16* __restrict__ Wh2b1, const u16* __restrict__ Wl2b1,
    const u16* __restrict__ Whenv0, const u16* __restrict__ Wlenv0,
    u16* __restrict__ latbuf, u16* __restrict__ featw,
    u16* __restrict__ envw, int E)
{
    __shared__ __align__(16) char sm[38912];
    u16 (*Xi)[32]  = (u16 (*)[32])sm;                     // 4096
    u16 (*Hs)[136] = (u16 (*)[136])(sm + 4096);           // 17408
    u16 (*Ls)[136] = (u16 (*)[136])(sm + 21504);          // 17408

    const int tid = threadIdx.x;
    const int lane = tid & 63;
    const int w = tid >> 6;
    const int e0 = blockIdx.x * 64;
    const int E1 = E - 1;
    const int r = lane & 15, q = lane >> 4;
    const bool full = (e0 + 64 <= E);

    // coalesced inv load: 64 rows x 8 floats contiguous (2KB)
    {
        int t = tid >> 3, c = tid & 7;
        Xi[t][c] = f2bf_hw(inv[(size_t)min(e0 + t, E1) * 8 + c]);
    }
    if (tid < 256) {                     // zero cols 8..31 (disjoint from loads)
        int t = tid >> 2, c = tid & 3;
        if (c) *(bf8_t*)&Xi[t][c * 8] = (bf8_t)(short)0;
    }
    __syncthreads();

    const f4_t z = {0.f, 0.f, 0.f, 0.f};
    f4_t acc[4];

    // GEMM1: inv(8->32) @ W2b0 -> silu -> Hs
#pragma unroll
    for (int s = 0; s < 4; ++s) acc[s] = z;
    gemm_rows<1, 4, 32>(&Xi[0][0], Wh2b0 + w * 512, Wl2b0 + w * 512, lane, acc);
#pragma unroll
    for (int s = 0; s < 4; ++s)
#pragma unroll
        for (int jj = 0; jj < 4; jj += 2) {
            u32 pk = cvtpk(silu_f(acc[s][jj] * RSQRT8), silu_f(acc[s][jj + 1] * RSQRT8));
            Hs[s * 16 + q * 4 + jj][w * 16 + r]     = (u16)pk;
            Hs[s * 16 + q * 4 + jj + 1][w * 16 + r] = (u16)(pk >> 16);
        }
    __syncthreads();

    // GEMM2: h(128) @ W2b1 -> lat -> Ls (latbuf written by bulk copy below)
#pragma unroll
    for (int s = 0; s < 4; ++s) acc[s] = z;
    gemm_rows<4, 4, 136>(&Hs[0][0], Wh2b1 + w * 4 * 512, Wl2b1 + w * 4 * 512, lane, acc);
#pragma unroll
    for (int s = 0; s < 4; ++s)
#pragma unroll
        for (int jj = 0; jj < 4; jj += 2) {
            int row0 = s * 16 + q * 4 + jj, cc = w * 16 + r;
            u32 pk = cvtpk(acc[s][jj] * RSQRT128, acc[s][jj + 1] * RSQRT128);
            Ls[row0][cc]     = (u16)pk;
            Ls[row0 + 1][cc] = (u16)(pk >> 16);
        }
    __syncthreads();

    // coalesced Ls -> latbuf (overlaps with GEMM3's MFMA work)
    for (int i = tid; i < 1024; i += 512) {
        int t = i >> 4, c = i & 15;
        int e = e0 + t;
        if (full || e < E)
            *(bf8_t*)(latbuf + (size_t)e * 128 + c * 8) = *(const bf8_t*)&Ls[t][c * 8];
    }

    // GEMM3: lat(128) @ Wenv0 -> w0; stage into Hs (dead), bulk-copy out.
#pragma unroll
    for (int s = 0; s < 4; ++s) acc[s] = z;
    gemm_rows<4, 4, 136>(&Ls[0][0], Whenv0 + w * 4 * 512, Wlenv0 + w * 4 * 512, lane, acc);
    {
        const int col = w * 16 + r;
#pragma unroll
        for (int s = 0; s < 4; ++s)
#pragma unroll
            for (int jj = 0; jj < 4; jj += 2) {
                int row0 = s * 16 + q * 4 + jj;
                u32 pk = cvtpk(acc[s][jj] * RSQRT128, acc[s][jj + 1] * RSQRT128);
                Hs[row0][col]     = (u16)pk;
                Hs[row0 + 1][col] = (u16)(pk >> 16);
            }
    }
    __syncthreads();
    for (int i = tid; i < 1024; i += 512) {
        int t = i >> 4, c = i & 15;
        int e = e0 + t;
        if (full || e < E) {
            u16* dst = (c < 8) ? (featw + (size_t)e * 64 + c * 8)
                               : (envw + (size_t)e * 64 + (c - 8) * 8);
            *(bf8_t*)dst = *(const bf8_t*)&Hs[t][c * 8];
        }
    }
}

// ---------------------------------------------------------------------------
// Phase B: tensor products (w0 x attr x env0 reconstructed in registers) +
// mix; new_lat MLP; lat2; w1 staged in X4 cols 128..191 -> coalesced envw.
// ---------------------------------------------------------------------------
__global__ __launch_bounds__(512, 6) void phaseB(
    const int* __restrict__ eidx, const float* __restrict__ attr,
    const u16* __restrict__ env0b,
    const u16* __restrict__ featw, u16* __restrict__ envw,
    const u16* __restrict__ Whs0, const u16* __restrict__ Wls0,
    const u16* __restrict__ Whv0, const u16* __restrict__ Wlv0,
    const u16* __restrict__ Whl10, const u16* __restrict__ Wll10,
    const u16* __restrict__ Whl11, const u16* __restrict__ Wll11,
    const u16* __restrict__ Whe1, const u16* __restrict__ Wle1,
    u16* __restrict__ latbuf, u16* __restrict__ featbuf, int E)
{
    __shared__ __align__(16) char sm[51200];
    u16 (*X4)[200] = (u16 (*)[200])sm;                    // 25600: lat|ss|vv -> lat2
    u16 (*P)[200]  = (u16 (*)[200])(sm + 25600);          // 25600: sv|vs per dim (192 used)
    u16 (*Hs)[136] = (u16 (*)[136])(sm + 25600);          // overlay P (dead post-mix)

    const int tid = threadIdx.x;
    const int lane = tid & 63;
    const int w = tid >> 6;
    const int e0 = blockIdx.x * 64;
    const int E1 = E - 1;
    const int r = lane & 15, q = lane >> 4;
    const bool full = (e0 + 64 <= E);

    // lat -> X4[:, 0:128]
    for (int i = tid; i < 64 * 16; i += 512) {
        int t = i >> 4, dc = i & 15;
        *(bf8_t*)&X4[t][dc * 8] = ((const bf8_t*)(latbuf + (size_t)min(e0 + t, E1) * 128))[dc];
    }

    // tensor-product pass: f-channels reconstructed from w0 row x attr.
    {
        const int t = tid >> 3, cg = tid & 7;
        const int e = min(e0 + t, E1);
        const int nd = eidx[e];
        bf8_t wv = *(const bf8_t*)(featw + (size_t)e * 64 + cg * 8);
        const u16* gp = env0b + (size_t)nd * 128 + cg * 16;
        bf8_t gA = *(const bf8_t*)gp;
        bf8_t gB = *(const bf8_t*)(gp + 8);
        float4 av = *(const float4*)(attr + (size_t)e * 4);
        float ssf[4], vvf[4], svf[3][4], vsf[3][4];
#pragma unroll
        for (int c = 0; c < 4; ++c) {
            float wf0 = bf2f((u16)wv[2 * c]);
            float wf1 = bf2f((u16)wv[2 * c + 1]);
            float f0 = wf0 * av.x, f1 = wf1 * av.y, f2 = wf1 * av.z, f3 = wf1 * av.w;
            float g0, g1, g2, g3;
            if (c < 2) {
                g0 = bf2f((u16)gA[4 * c]);     g1 = bf2f((u16)gA[4 * c + 1]);
                g2 = bf2f((u16)gA[4 * c + 2]); g3 = bf2f((u16)gA[4 * c + 3]);
            } else {
                int cc = c - 2;
                g0 = bf2f((u16)gB[4 * cc]);     g1 = bf2f((u16)gB[4 * cc + 1]);
                g2 = bf2f((u16)gB[4 * cc + 2]); g3 = bf2f((u16)gB[4 * cc + 3]);
            }
            ssf[c] = f0 * g0;
            vvf[c] = (f1 * g1 + f2 * g2 + f3 * g3) * INV_SQRT3;
            svf[0][c] = f0 * g1;  svf[1][c] = f0 * g2;  svf[2][c] = f0 * g3;
            vsf[0][c] = f1 * g0;  vsf[1][c] = f2 * g0;  vsf[2][c] = f3 * g0;
        }
        *(uint2*)&X4[t][128 + 4 * cg] = make_uint2(cvtpk(ssf[0], ssf[1]), cvtpk(ssf[2], ssf[3]));
        *(uint2*)&X4[t][160 + 4 * cg] = make_uint2(cvtpk(vvf[0], vvf[1]), cvtpk(vvf[2], vvf[3]));
#pragma unroll
        for (int d = 0; d < 3; ++d) {
            *(uint2*)&P[t][d * 64 + 4 * cg]      = make_uint2(cvtpk(svf[d][0], svf[d][1]), cvtpk(svf[d][2], svf[d][3]));
            *(uint2*)&P[t][d * 64 + 32 + 4 * cg] = make_uint2(cvtpk(vsf[d][0], vsf[d][1]), cvtpk(vsf[d][2], vsf[d][3]));
        }
    }
    __syncthreads();

    const f4_t z = {0.f, 0.f, 0.f, 0.f};

    // ---- mix: wave = (strip sw, col-half cw); B-frags loaded once, shared
    // across S and all 3 V dims.
    {
        const int sw = w >> 1, cw = w & 1;
        f4_t aS = z, aV[3] = {z, z, z};
        const u16* bsh = Whs0 + cw * 2 * 512;
        const u16* bsl = Wls0 + cw * 2 * 512;
        const u16* bvh = Whv0 + cw * 2 * 512;
        const u16* bvl = Wlv0 + cw * 2 * 512;
        bf8_t s0h = *(const bf8_t*)(bsh + lane * 8);
        bf8_t s0l = *(const bf8_t*)(bsl + lane * 8);
        bf8_t s1h = *(const bf8_t*)(bsh + 512 + lane * 8);
        bf8_t s1l = *(const bf8_t*)(bsl + 512 + lane * 8);
        bf8_t v0h = *(const bf8_t*)(bvh + lane * 8);
        bf8_t v0l = *(const bf8_t*)(bvl + lane * 8);
        bf8_t v1h = *(const bf8_t*)(bvh + 512 + lane * 8);
        bf8_t v1l = *(const bf8_t*)(bvl + 512 + lane * 8);
        const u16* arow = &X4[sw * 16 + r][0];
        bf8_t a0 = *(const bf8_t*)(arow + 128 + q * 8);
        bf8_t a1 = *(const bf8_t*)(arow + 160 + q * 8);
        aS = MFMA16(a0, s0l, aS, 0, 0, 0);
        aS = MFMA16(a0, s0h, aS, 0, 0, 0);
        aS = MFMA16(a1, s1l, aS, 0, 0, 0);
        aS = MFMA16(a1, s1h, aS, 0, 0, 0);
        const u16* prow = &P[sw * 16 + r][0];
#pragma unroll
        for (int d = 0; d < 3; ++d) {
            bf8_t p0 = *(const bf8_t*)(prow + d * 64 + q * 8);
            bf8_t p1 = *(const bf8_t*)(prow + d * 64 + 32 + q * 8);
            aV[d] = MFMA16(p0, v0l, aV[d], 0, 0, 0);
            aV[d] = MFMA16(p0, v0h, aV[d], 0, 0, 0);
            aV[d] = MFMA16(p1, v1l, aV[d], 0, 0, 0);
            aV[d] = MFMA16(p1, v1h, aV[d], 0, 0, 0);
        }
        // feat2 direct to global: one 8B store per reg (128B/16-lane group)
        const int m = cw * 16 + r;
#pragma unroll
        for (int reg = 0; reg < 4; ++reg) {
            int e = e0 + sw * 16 + q * 4 + reg;
            if (full || e < E) {
                uint2 pv;
                pv.x = cvtpk(aS[reg] * RSQRT64,
                             aV[0][reg] * (RSQRT64 * INV_SQRT3));
                pv.y = cvtpk(aV[1][reg] * (RSQRT64 * INV_SQRT3),
                             aV[2][reg] * (RSQRT64 * INV_SQRT3));
                *(uint2*)(featbuf + (size_t)e * 128 + 4 * m) = pv;
            }
        }
    }

    // GEMM4: [lat|sscal](192) @ Wlat1_0
    f4_t acc[4];
#pragma unroll
    for (int s = 0; s < 4; ++s) acc[s] = z;
    gemm_rows<6, 4, 200>(&X4[0][0], Whl10 + w * 6 * 512, Wll10 + w * 6 * 512, lane, acc);
    __syncthreads();   // all P reads (mix) done -> Hs may overwrite P
#pragma unroll
    for (int s = 0; s < 4; ++s)
#pragma unroll
        for (int jj = 0; jj < 4; jj += 2) {
            u32 pk = cvtpk(silu_f(acc[s][jj] * RSQRT192), silu_f(acc[s][jj + 1] * RSQRT192));
            Hs[s * 16 + q * 4 + jj][w * 16 + r]     = (u16)pk;
            Hs[s * 16 + q * 4 + jj + 1][w * 16 + r] = (u16)(pk >> 16);
        }
    __syncthreads();

    // GEMM5: h @ Wlat1_1 -> new_lat; lat2 = C*(lat+new_lat) in place in X4
#pragma unroll
    for (int s = 0; s < 4; ++s) acc[s] = z;
    gemm_rows<4, 4, 136>(&Hs[0][0], Whl11 + w * 4 * 512, Wll11 + w * 4 * 512, lane, acc);
#pragma unroll
    for (int s = 0; s < 4; ++s)
#pragma unroll
        for (int jj = 0; jj < 4; jj += 2) {
            int row0 = s * 16 + q * 4 + jj, cc = w * 16 + r;
            float l2a = C_HALF * (bf2f(X4[row0][cc]) + acc[s][jj] * RSQRT128);
            float l2b = C_HALF * (bf2f(X4[row0 + 1][cc]) + acc[s][jj + 1] * RSQRT128);
            u32 pk = cvtpk(l2a, l2b);
            X4[row0][cc]     = (u16)pk;       // cells owned by this lane-reg only
            X4[row0 + 1][cc] = (u16)(pk >> 16);
        }
    __syncthreads();

    // lat2 -> latbuf (coalesced) ; GEMM6: lat2 @ Wenv1 -> w1 staged in X4
    for (int i = tid; i < 64 * 16; i += 512) {
        int t = i >> 4, dc = i & 15;
        int e = e0 + t;
        if (full || e < E)
            ((bf8_t*)(latbuf + (size_t)e * 128))[dc] = *(const bf8_t*)&X4[t][dc * 8];
    }
    {
        const int ct = w & 3, rh = w >> 2;   // col tile 0..3, row half 0..1
        f4_t a6[2] = {z, z};
        gemm_rows<4, 2, 200>(&X4[rh * 32][0], Whe1 + ct * 4 * 512, Wle1 + ct * 4 * 512, lane, a6);
        const int col = ct * 16 + r;         // 0..63
#pragma unroll
        for (int s = 0; s < 2; ++s)
#pragma unroll
            for (int jj = 0; jj < 4; jj += 2) {
                int row0 = rh * 32 + s * 16 + q * 4 + jj;
                u32 pk = cvtpk(a6[s][jj] * RSQRT128, a6[s][jj + 1] * RSQRT128);
                X4[row0][128 + col]     = (u16)pk;     // stage (cols 128.. dead)
                X4[row0 + 1][128 + col] = (u16)(pk >> 16);
            }
    }
    __syncthreads();
    // coalesced w1 copy: 64 rows x 64 u16 = 512 chunks of 16B
    {
        int t = tid >> 3, c = tid & 7;
        int e = e0 + t;
        if (full || e < E)
            *(bf8_t*)(envw + (size_t)e * 64 + c * 8) = *(const bf8_t*)&X4[t][128 + c * 8];
    }
}

// ---------------------------------------------------------------------------
// Phase C (R5 version): scalars1 streamed from global, final MLP, out mix.
// ---------------------------------------------------------------------------
__global__ __launch_bounds__(512, 6) void phaseC(
    const int* __restrict__ eidx, const u16* __restrict__ env1b,
    const u16* __restrict__ Whf0, const u16* __restrict__ Wlf0,
    const u16* __restrict__ Whf1, const u16* __restrict__ Wlf1,
    const u16* __restrict__ latbuf, const u16* __restrict__ featbuf,
    float* __restrict__ outp, int E)
{
    __shared__ __align__(16) char sm[43008];
    u16 (*X7)[200] = (u16 (*)[200])sm;                    // 25600: lat2|scal1
    u16 (*Hs)[136] = (u16 (*)[136])(sm + 25600);          // 17408

    const int tid = threadIdx.x;
    const int lane = tid & 63;
    const int w = tid >> 6;
    const int e0 = blockIdx.x * 64;
    const int E1 = E - 1;
    const int r = lane & 15, q = lane >> 4;
    const bool full = (e0 + 64 <= E);

    // lat2 -> X7[:, 0:128]
    for (int i = tid; i < 64 * 16; i += 512) {
        int t = i >> 4, dc = i & 15;
        *(bf8_t*)&X7[t][dc * 8] = ((const bf8_t*)(latbuf + (size_t)min(e0 + t, E1) * 128))[dc];
    }

    // scalars1 pass: ss/vv from feat2 x env1, streamed from global
    {
        const int t = tid >> 3, cg = tid & 7;
        const int e = min(e0 + t, E1);
        const int nd = eidx[e];
        const u16* fp = featbuf + (size_t)e * 128 + cg * 16;
        const u16* gp = env1b + (size_t)nd * 128 + cg * 16;
        bf8_t fA = *(const bf8_t*)fp;
        bf8_t fB = *(const bf8_t*)(fp + 8);
        bf8_t gA = *(const bf8_t*)gp;
        bf8_t gB = *(const bf8_t*)(gp + 8);
        float ssf[4], vvf[4];
#pragma unroll
        for (int c = 0; c < 4; ++c) {
            float f0, f1, f2, f3, g0, g1, g2, g3;
            if (c < 2) {
                f0 = bf2f((u16)fA[4 * c]);     g0 = bf2f((u16)gA[4 * c]);
                f1 = bf2f((u16)fA[4 * c + 1]); g1 = bf2f((u16)gA[4 * c + 1]);
                f2 = bf2f((u16)fA[4 * c + 2]); g2 = bf2f((u16)gA[4 * c + 2]);
                f3 = bf2f((u16)fA[4 * c + 3]); g3 = bf2f((u16)gA[4 * c + 3]);
            } else {
                int cc = c - 2;
                f0 = bf2f((u16)fB[4 * cc]);     g0 = bf2f((u16)gB[4 * cc]);
                f1 = bf2f((u16)fB[4 * cc + 1]); g1 = bf2f((u16)gB[4 * cc + 1]);
                f2 = bf2f((u16)fB[4 * cc + 2]); g2 = bf2f((u16)gB[4 * cc + 2]);
                f3 = bf2f((u16)fB[4 * cc + 3]); g3 = bf2f((u16)gB[4 * cc + 3]);
            }
            ssf[c] = f0 * g0;
            vvf[c] = (f1 * g1 + f2 * g2 + f3 * g3) * INV_SQRT3;
        }
        *(uint2*)&X7[t][128 + 4 * cg] = make_uint2(cvtpk(ssf[0], ssf[1]), cvtpk(ssf[2], ssf[3]));
        *(uint2*)&X7[t][160 + 4 * cg] = make_uint2(cvtpk(vvf[0], vvf[1]), cvtpk(vvf[2], vvf[3]));
    }
    __syncthreads();

    const f4_t z = {0.f, 0.f, 0.f, 0.f};
    f4_t acc[4];
#pragma unroll
    for (int s = 0; s < 4; ++s) acc[s] = z;
    gemm_rows<6, 4, 200>(&X7[0][0], Whf0 + w * 6 * 512, Wlf0 + w * 6 * 512, lane, acc);
    // Hs is a fresh region (disjoint from X7) -> no barrier needed before writes
#pragma unroll
    for (int s = 0; s < 4; ++s)
#pragma unroll
        for (int jj = 0; jj < 4; jj += 2) {
            u32 pk = cvtpk(silu_f(acc[s][jj] * RSQRT192), silu_f(acc[s][jj + 1] * RSQRT192));
            Hs[s * 16 + q * 4 + jj][w * 16 + r]     = (u16)pk;
            Hs[s * 16 + q * 4 + jj + 1][w * 16 + r] = (u16)(pk >> 16);
        }
    __syncthreads();

#pragma unroll
    for (int s = 0; s < 4; ++s) acc[s] = z;
    gemm_rows<4, 4, 136>(&Hs[0][0], Whf1 + w * 4 * 512, Wlf1 + w * 4 * 512, lane, acc);
    if (full) {
#pragma unroll
        for (int s = 0; s < 4; ++s)
#pragma unroll
            for (int jj = 0; jj < 4; ++jj) {
                int row = s * 16 + q * 4 + jj, cc = w * 16 + r;
                outp[(size_t)(e0 + row) * 128 + cc] =
                    SQ23 * bf2f(X7[row][cc]) + SQ13 * (acc[s][jj] * RSQRT128);
            }
    } else {
#pragma unroll
        for (int s = 0; s < 4; ++s)
#pragma unroll
            for (int jj = 0; jj < 4; ++jj) {
                int row = s * 16 + q * 4 + jj, cc = w * 16 + r;
                int e = e0 + row;
                if (e < E)
                    outp[(size_t)e * 128 + cc] =
                        SQ23 * bf2f(X7[row][cc]) + SQ13 * (acc[s][jj] * RSQRT128);
            }
    }
}

extern "C" void kernel_launch(void* const* d_in, const int* in_sizes, int n_in,
                              void* d_out, int out_size, void* d_ws, size_t ws_size,
                              hipStream_t stream)
{
    const int E  = in_sizes[0] / 2;
    const int NN = 12500;

    const int*   eidx    = (const int*)d_in[0];
    const float* attr    = (const float*)d_in[1];
    const float* inv     = (const float*)d_in[2];
    float* outp = (float*)d_out;

    // ws: lat bf16 | feat2 bf16 | env0b, env1b bf16 | weights | sort ints
    u16* latbuf  = (u16*)d_ws;
    u16* featbuf = latbuf + (size_t)E * 128;
    u16* env0b   = featbuf + (size_t)E * 128;
    u16* env1b   = env0b + (size_t)NN * 128;
    u16* p = env1b + (size_t)NN * 128;
    auto carve = [&](int elems) { u16* q0 = p; p += elems; return q0; };
    u16 *Wh2b0 = carve(128 * 32),  *Wl2b0 = carve(128 * 32);
    u16 *Wh2b1 = carve(128 * 128), *Wl2b1 = carve(128 * 128);
    u16 *Whe0  = carve(128 * 128), *Wle0  = carve(128 * 128);
    u16 *Whl10 = carve(128 * 192), *Wll10 = carve(128 * 192);
    u16 *Whl11 = carve(128 * 128), *Wll11 = carve(128 * 128);
    u16 *Whe1  = carve(64 * 128),  *Wle1  = carve(64 * 128);
    u16 *Whs0  = carve(32 * 64),   *Wls0  = carve(32 * 64);
    u16 *Whv0  = carve(32 * 64),   *Wlv0  = carve(32 * 64);
    u16 *Whf0  = carve(128 * 192), *Wlf0  = carve(128 * 192);
    u16 *Whf1  = carve(128 * 128), *Wlf1  = carve(128 * 128);
    int* cnt;
    {
        size_t off_bytes = (size_t)((char*)p - (char*)d_ws);
        off_bytes = (off_bytes + 3) & ~(size_t)3;
        cnt = (int*)((char*)d_ws + off_bytes);
    }
    int* base   = cnt + NN;          // NN+1 entries
    int* cursor = base + NN + 1;
    int* sorted = cursor + NN;

    // w-space scratch lives in d_out (fully overwritten by phaseC afterwards):
    // featw = w0[:, :64] rows, envw = w0[:,64:] rows then w1 rows.
    u16* featw = (u16*)d_out;
    u16* envw  = featw + (size_t)E * 64;

    hipMemsetAsync(cnt, 0, NN * sizeof(int), stream);

    // ---- weight prep (source-linear) + edge histogram (one kernel) ----
    PDs P;
    auto setpd = [&](int i, const float* s, u16* h, u16* l, int Nsh, int Kp, int pm, int off, int c) {
        P.d[i] = {s, h, l, Nsh, Kp, pm, off, c};
    };
    setpd(0, (const float*)d_in[3],  Wh2b0, Wl2b0, 7,  32, 0, 0,      1024);
    setpd(1, (const float*)d_in[4],  Wh2b1, Wl2b1, 7, 128, 0, 1024,   16384);
    setpd(2, (const float*)d_in[5],  Whe0,  Wle0,  7, 128, 0, 17408,  16384);
    setpd(3, (const float*)d_in[6],  Whl10, Wll10, 7, 192, 1, 33792,  24576);
    setpd(4, (const float*)d_in[7],  Whl11, Wll11, 7, 128, 0, 58368,  16384);
    setpd(5, (const float*)d_in[8],  Whe1,  Wle1,  6, 128, 0, 74752,  8192);
    setpd(6, (const float*)d_in[9],  Whs0,  Wls0,  5,  64, 0, 82944,  2048);
    setpd(7, (const float*)d_in[10], Whv0,  Wlv0,  5,  64, 0, 84992,  2048);
    setpd(8, (const float*)d_in[11], Whf0,  Wlf0,  7, 192, 1, 87040,  24576);
    setpd(9, (const float*)d_in[12], Whf1,  Wlf1,  7, 128, 0, 111616, 16384);
    const int total = 128000;            // + 3072 pad handled in-kernel
    const int span = (E > total + 3072) ? E : (total + 3072);
    prep_all<<<(span + 255) / 256, 256, 0, stream>>>(P, total, eidx, cnt, E);

    // ---- counting sort of edges by center node ----
    scan_k<<<1, 1024, 0, stream>>>(cnt, base, cursor, NN);
    scatter_k<<<(E + 255) / 256, 256, 0, stream>>>(eidx, cursor, sorted, E);

    const int nb = (E + 63) / 64;
    phaseA<<<nb, 512, 0, stream>>>(inv, Wh2b0, Wl2b0, Wh2b1, Wl2b1,
                                   Whe0, Wle0, latbuf, featw, envw, E);
    reduce_env<<<(NN + 3) / 4, 256, 0, stream>>>(base, sorted, envw, attr, env0b, NN);
    phaseB<<<nb, 512, 0, stream>>>(eidx, attr, env0b, featw, envw,
                                   Whs0, Wls0, Whv0, Wlv0,
                                   Whl10, Wll10, Whl11, Wll11, Whe1, Wle1,
                                   latbuf, featbuf, E);
    reduce_env<<<(NN + 3) / 4, 256, 0, stream>>>(base, sorted, envw, attr, env1b, NN);
    phaseC<<<nb, 512, 0, stream>>>(eidx, env1b, Whf0, Wlf0, Whf1, Wlf1,
                                   latbuf, featbuf, outp, E);
}